// Round 6
// baseline (191.718 us; speedup 1.0000x reference)
//
#include <hip/hip_runtime.h>
#include <math.h>

#define BATCH 32
#define CIN   256
#define LEN   8192
#define HL    (LEN/2)
#define ORD   8
#define NPOS  (BATCH*LEN)   // 262144 positions

struct Params { const float* p[32]; };

// Input index map (setup_inputs dict order):
// 0 x, 1 conv1_w, 2 conv1_b, 3 conv2_b
// w_ branch: 4 c1w, 5 c1b, 6 c2w, 7 c2b, 8 g1, 9 g2, 10 g3, 11 b1, 12 b2,
//            13 b3, 14 pxw, 15 pxb, 16 fcw, 17 fcb        (c_ branch = +14)
// ws: [0:32) conv sum  [32:64) conv sumsq  [64:80) cpre sum  [80:96) cpre sumsq
//     [96:608) per-sample c sums: 96 + br*256 + b*8 + ch
//     [608:640) per-sample int counters (zeroed by the 4 KiB memset)

__device__ __forceinline__ void wave_reduce2(float& sv, float& sq)
{
#pragma unroll
    for (int m = 32; m >= 1; m >>= 1) {
        sv += __shfl_xor(sv, m, 64);
        sq += __shfl_xor(sq, m, 64);
    }
}
__device__ __forceinline__ void wave_reduce1(float& sv)
{
#pragma unroll
    for (int m = 32; m >= 1; m >>= 1) sv += __shfl_xor(sv, m, 64);
}

// conv weights staged in LDS: wl[(bc*8+o)*24 + i*3 + k]
__device__ __forceinline__ void load_conv_lds(const Params& P, float* wl, float* bl, int tid)
{
    for (int idx = tid; idx < 4*192; idx += 256) {
        int which = idx / 192, s = idx - which*192;
        const float* src = (which==0) ? P.p[4] : (which==1) ? P.p[6]
                         : (which==2) ? P.p[18] : P.p[20];
        wl[idx] = src[s];
    }
    if (tid < 32) {
        int wq = tid >> 3, o = tid & 7;
        const float* bsrc = (wq==0) ? P.p[5] : (wq==1) ? P.p[7]
                          : (wq==2) ? P.p[19] : P.p[21];
        bl[tid] = bsrc[o];
    }
}

// conv pre-act pair (positions p, p+1); weights via wave-uniform float4 LDS
// broadcasts. row = bc*8+o.
__device__ __forceinline__ void conv6_pair_lds(
    const float xv[8][6], const float* wl, float bv, int dil, int row,
    float& r0, float& r1)
{
    float a0 = bv, a1 = bv;
    const float4* wr4 = reinterpret_cast<const float4*>(wl + row*24);
    float wr[24];
#pragma unroll
    for (int q = 0; q < 6; q++) *reinterpret_cast<float4*>(&wr[4*q]) = wr4[q];
#pragma unroll
    for (int i = 0; i < 8; i++) {
        float w0 = wr[i*3+0], w1 = wr[i*3+1], w2 = wr[i*3+2];
        if (dil == 1) {
            a0 += w0*xv[i][1] + w1*xv[i][2] + w2*xv[i][3];
            a1 += w0*xv[i][2] + w1*xv[i][3] + w2*xv[i][4];
        } else {
            a0 += w0*xv[i][0] + w1*xv[i][2] + w2*xv[i][4];
            a1 += w0*xv[i][1] + w1*xv[i][3] + w2*xv[i][5];
        }
    }
    r0 = a0; r1 = a1;
}

// stage x1 tile [t0-2, t0+514) into xt[ch][2..517], interior at offset 4
template<int W>
__device__ __forceinline__ void stage_tile(
    const float* __restrict__ x1, int b, int t0, float (*xt)[W], int tid)
{
    int ch = tid >> 5, q = tid & 31;
    const float* src = x1 + ((size_t)b*ORD + ch)*LEN + t0 + q*16;
    float4* dst = reinterpret_cast<float4*>(&xt[ch][4 + q*16]);
#pragma unroll
    for (int j = 0; j < 4; j++) dst[j] = reinterpret_cast<const float4*>(src)[j];
    if (tid < 32) {
        int hc = tid >> 2, hh = tid & 3;
        int l   = t0 + ((hh < 2) ? (hh - 2) : (510 + hh));   // -2,-1,512,513
        int idx = (hh < 2) ? (2 + hh) : (514 + hh);          // 2,3,516,517
        xt[hc][idx] = ((unsigned)l < (unsigned)LEN)
                    ? x1[((size_t)b*ORD + hc)*LEN + l] : 0.f;
    }
}

#define LOAD_XV6(xt, tid, xv)                                 \
    _Pragma("unroll")                                         \
    for (int i_ = 0; i_ < 8; i_++) {                          \
        _Pragma("unroll")                                     \
        for (int d_ = 0; d_ < 6; d_++)                        \
            xv[i_][d_] = xt[i_][2 + 2*(tid) + d_];            \
    }

// ---------------------------------------------------------------------------
// K1: pointwise GEMM -> x1 + fused bn1/bn2 stats (halo x prefetched)
// ---------------------------------------------------------------------------
__global__ __launch_bounds__(256, 2) void k1_gemm_stats(
    const float* __restrict__ x, const float* __restrict__ w,
    const float* __restrict__ bias, float* __restrict__ x1,
    float* __restrict__ ws, Params P)
{
    __shared__ float wt[CIN][ORD];     // conv1 weights wt[i][o]
    __shared__ float xt[ORD][528];
    __shared__ float hbuf[4][257];
    __shared__ float wl[768], bl[32];
    __shared__ float part[256];
    int tid = threadIdx.x;
    for (int idx = tid; idx < CIN*ORD; idx += 256) {
        int o = idx >> 8, i = idx & 255;          // source layout [o][i]
        wt[i][o] = w[idx];
    }
    load_conv_lds(P, wl, bl, tid);

    int b  = blockIdx.x >> 4;
    int t0 = (blockIdx.x & 15) << 9;

    // halo-x prefetch (consumed after the stream loop; latency hidden)
    const float* xch = x + ((size_t)b*CIN + tid)*LEN;
    float h0 = 0.f, h1 = 0.f, h2 = 0.f, h3 = 0.f;
    if (t0 >= 2)        { h0 = xch[t0-2];   h1 = xch[t0-1]; }
    if (t0 + 513 < LEN) { h2 = xch[t0+512]; h3 = xch[t0+513]; }
    __syncthreads();

    const float2* xrow = reinterpret_cast<const float2*>(x)
                       + (size_t)b*CIN*HL + (t0 >> 1) + tid;
    float2 acc[ORD];
#pragma unroll
    for (int o = 0; o < ORD; o++) { acc[o].x = 0.f; acc[o].y = 0.f; }

#pragma unroll 8
    for (int i = 0; i < CIN; i++) {
        float2 xv2 = xrow[(size_t)i * HL];
        const float4* wr = reinterpret_cast<const float4*>(&wt[i][0]);
        float4 wa = wr[0], wb = wr[1];
        acc[0].x += xv2.x*wa.x; acc[0].y += xv2.y*wa.x;
        acc[1].x += xv2.x*wa.y; acc[1].y += xv2.y*wa.y;
        acc[2].x += xv2.x*wa.z; acc[2].y += xv2.y*wa.z;
        acc[3].x += xv2.x*wa.w; acc[3].y += xv2.y*wa.w;
        acc[4].x += xv2.x*wb.x; acc[4].y += xv2.y*wb.x;
        acc[5].x += xv2.x*wb.y; acc[5].y += xv2.y*wb.y;
        acc[6].x += xv2.x*wb.z; acc[6].y += xv2.y*wb.z;
        acc[7].x += xv2.x*wb.w; acc[7].y += xv2.y*wb.w;
    }

    float2* x1row = reinterpret_cast<float2*>(x1)
                  + (size_t)b*ORD*HL + (t0 >> 1) + tid;
#pragma unroll
    for (int o = 0; o < ORD; o++) {
        float bo = bias[o];
        float2 r; r.x = acc[o].x + bo; r.y = acc[o].y + bo;
        x1row[(size_t)o * HL] = r;
        *reinterpret_cast<float2*>(&xt[o][4 + 2*tid]) = r;
    }
    hbuf[0][tid] = h0; hbuf[1][tid] = h1; hbuf[2][tid] = h2; hbuf[3][tid] = h3;
    __syncthreads();

    // halo x1 (-2,-1,512,513) from LDS-held x columns
    if (tid < 32) {
        int hq = tid >> 3, ch = tid & 7;
        int l  = t0 + ((hq < 2) ? (hq - 2) : (510 + hq));
        float a = 0.f;
        if ((unsigned)l < (unsigned)LEN) {
            a = bias[ch];
#pragma unroll 8
            for (int i = 0; i < CIN; i++) a += hbuf[hq][i] * wt[i][ch];
        }
        int idx = (hq < 2) ? (2 + hq) : (514 + hq);
        xt[ch][idx] = a;
    }
    __syncthreads();

    float xv[8][6];
    LOAD_XV6(xt, tid, xv);

    int lane = tid & 63, wv = tid >> 6;
#pragma unroll
    for (int grp = 0; grp < 4; grp++) {
        int dil = (grp & 1) ? 2 : 1;
#pragma unroll
        for (int o = 0; o < 8; o++) {
            int c = grp*8 + o;
            float a0, a1;
            conv6_pair_lds(xv, wl, bl[c], dil, c, a0, a1);
            float sv = a0 + a1, sq = a0*a0 + a1*a1;
            wave_reduce2(sv, sq);
            if (lane == 0) { part[c*4 + wv] = sv; part[(32+c)*4 + wv] = sq; }
        }
    }
    __syncthreads();
    if (tid < 64) {
        float s = part[tid*4] + part[tid*4+1] + part[tid*4+2] + part[tid*4+3];
        atomicAdd(&ws[tid], s);
    }
}

// ---------------------------------------------------------------------------
// K3: bn1/bn2+relu, pointwise conv -> c_pre (registers only); bn3 stats
// ---------------------------------------------------------------------------
__global__ __launch_bounds__(256, 2) void k3_stats(
    const float* __restrict__ x1, float* __restrict__ ws, Params P)
{
    __shared__ float wl[768], bl[32];
    __shared__ float pxl[128], pxbl[16];
    __shared__ float scl[32], shf[32];
    __shared__ float xt[ORD][528];
    __shared__ float part[128];
    int tid = threadIdx.x;
    load_conv_lds(P, wl, bl, tid);
    if (tid >= 128) { int q = tid - 128; pxl[q] = (q < 64) ? P.p[14][q] : P.p[28][q-64]; }
    if (tid >= 112 && tid < 128) { int q = tid - 112; pxbl[q] = (q < 8) ? P.p[15][q] : P.p[29][q-8]; }
    if (tid >= 32 && tid < 64) {
        int c = tid - 32;
        int br = c >> 4, cv = (c >> 3) & 1, o = c & 7;
        const float Ninv = 1.0f / (float)NPOS;
        float m   = ws[c]      * Ninv;
        float var = ws[32 + c] * Ninv - m*m;
        const float* g  = P.p[ br ? (cv?23:22) : (cv?9:8)  ];
        const float* be = P.p[ br ? (cv?26:25) : (cv?12:11)];
        float sc = g[o] * rsqrtf(var + 1e-5f);
        scl[c] = sc; shf[c] = be[o] - m*sc;
    }
    int b  = blockIdx.x >> 4;
    int t0 = (blockIdx.x & 15) << 9;
    stage_tile<528>(x1, b, t0, xt, tid);
    __syncthreads();

    float xv[8][6];
    LOAD_XV6(xt, tid, xv);

    int lane = tid & 63, wv = tid >> 6;
#pragma unroll
    for (int br = 0; br < 2; br++) {
        float s0[8], s1[8];
#pragma unroll
        for (int ch = 0; ch < 8; ch++) {
            int ca = (br*2+0)*8 + ch, cb = (br*2+1)*8 + ch;
            float a0, a1, c0, c1;
            conv6_pair_lds(xv, wl, bl[ca], 1, ca, a0, a1);
            conv6_pair_lds(xv, wl, bl[cb], 2, cb, c0, c1);
            s0[ch] = fmaxf(a0*scl[ca] + shf[ca], 0.f) + fmaxf(c0*scl[cb] + shf[cb], 0.f);
            s1[ch] = fmaxf(a1*scl[ca] + shf[ca], 0.f) + fmaxf(c1*scl[cb] + shf[cb], 0.f);
        }
#pragma unroll
        for (int o = 0; o < 8; o++) {
            float a0 = pxbl[br*8 + o], a1 = a0;
#pragma unroll
            for (int i = 0; i < 8; i++) {
                a0 += pxl[br*64 + o*8 + i] * s0[i];
                a1 += pxl[br*64 + o*8 + i] * s1[i];
            }
            int c = br*8 + o;
            float sv = a0 + a1, sq = a0*a0 + a1*a1;
            wave_reduce2(sv, sq);
            if (lane == 0) { part[c*4 + wv] = sv; part[(16+c)*4 + wv] = sq; }
        }
    }
    __syncthreads();
    if (tid < 32) {
        float s = part[tid*4] + part[tid*4+1] + part[tid*4+2] + part[tid*4+3];
        atomicAdd(&ws[64 + tid], s);
    }
}

// ---------------------------------------------------------------------------
// K46: recompute c = relu(bn3(cpre)), per-sample pooled sums (atomic);
// LAST block per sample: fc -> Hermite kernel -> whole-sample 8x9 conv -> out
// ---------------------------------------------------------------------------
#define SROW 1040
__global__ __launch_bounds__(256, 2) void k46_pool_out(
    const float* __restrict__ x1, float* __restrict__ ws, Params P,
    float* __restrict__ out)
{
    __shared__ float wl[768], bl[32];
    __shared__ float pxl[128], pxbl[16];
    __shared__ float scl[32], shf[32], scl3[16], shf3[16];
    __shared__ float smem[ORD][SROW];   // phase A: x1 tile; phase B: chunk tile
    __shared__ float part[64];
    __shared__ float kern[8][9];
    __shared__ int amLast;
    int tid = threadIdx.x;
    const float Ninv = 1.0f / (float)NPOS;
    load_conv_lds(P, wl, bl, tid);
    if (tid >= 128) { int q = tid - 128; pxl[q] = (q < 64) ? P.p[14][q] : P.p[28][q-64]; }
    if (tid >= 112 && tid < 128) { int q = tid - 112; pxbl[q] = (q < 8) ? P.p[15][q] : P.p[29][q-8]; }
    if (tid >= 32 && tid < 64) {
        int c = tid - 32;
        int br = c >> 4, cv = (c >> 3) & 1, o = c & 7;
        float m   = ws[c]      * Ninv;
        float var = ws[32 + c] * Ninv - m*m;
        const float* g  = P.p[ br ? (cv?23:22) : (cv?9:8)  ];
        const float* be = P.p[ br ? (cv?26:25) : (cv?12:11)];
        float sc = g[o] * rsqrtf(var + 1e-5f);
        scl[c] = sc; shf[c] = be[o] - m*sc;
    }
    if (tid >= 64 && tid < 80) {
        int c = tid - 64;
        int br = c >> 3, o = c & 7;
        float m3 = ws[64 + c] * Ninv;
        float v3 = ws[80 + c] * Ninv - m3*m3;
        const float* g3 = P.p[ br ? 24 : 10 ];
        const float* b3 = P.p[ br ? 27 : 13 ];
        float sc = g3[o] * rsqrtf(v3 + 1e-5f);
        scl3[c] = sc; shf3[c] = b3[o] - m3*sc;
    }
    int b  = blockIdx.x >> 4;
    int t0 = (blockIdx.x & 15) << 9;
    stage_tile<SROW>(x1, b, t0, smem, tid);
    __syncthreads();

    float xv[8][6];
    LOAD_XV6(smem, tid, xv);

    int lane = tid & 63, wv = tid >> 6;
#pragma unroll
    for (int br = 0; br < 2; br++) {
        float s0[8], s1[8];
#pragma unroll
        for (int ch = 0; ch < 8; ch++) {
            int ca = (br*2+0)*8 + ch, cb = (br*2+1)*8 + ch;
            float a0, a1, c0, c1;
            conv6_pair_lds(xv, wl, bl[ca], 1, ca, a0, a1);
            conv6_pair_lds(xv, wl, bl[cb], 2, cb, c0, c1);
            s0[ch] = fmaxf(a0*scl[ca] + shf[ca], 0.f) + fmaxf(c0*scl[cb] + shf[cb], 0.f);
            s1[ch] = fmaxf(a1*scl[ca] + shf[ca], 0.f) + fmaxf(c1*scl[cb] + shf[cb], 0.f);
        }
#pragma unroll
        for (int o = 0; o < 8; o++) {
            float a0 = pxbl[br*8 + o], a1 = a0;
#pragma unroll
            for (int i = 0; i < 8; i++) {
                a0 += pxl[br*64 + o*8 + i] * s0[i];
                a1 += pxl[br*64 + o*8 + i] * s1[i];
            }
            int c = br*8 + o;
            float sv = fmaxf(a0*scl3[c] + shf3[c], 0.f)
                     + fmaxf(a1*scl3[c] + shf3[c], 0.f);
            wave_reduce1(sv);
            if (lane == 0) part[c*4 + wv] = sv;
        }
    }
    __syncthreads();
    if (tid < 16) {
        float s = part[tid*4] + part[tid*4+1] + part[tid*4+2] + part[tid*4+3];
        atomicAdd(&ws[96 + (tid >> 3)*256 + b*8 + (tid & 7)], s);
    }
    __threadfence();                     // pooled adds visible before counter
    __syncthreads();
    if (tid == 0) {
        int* cnt = (int*)(ws + 608);
        int old = atomicAdd(&cnt[b], 1);
        amLast = (old == 15);
    }
    __syncthreads();
    if (!amLast) return;                 // block-uniform exit
    __threadfence();                     // acquire: see other blocks' adds

    // ---- last block of sample b: fc -> Hermite kernel ----
    if (tid < 9) {
        const volatile float* wsp = ws;
        const float Li = 1.0f / (float)LEN;
        float vw = P.p[17][0], vc = P.p[31][0];
#pragma unroll
        for (int ch = 0; ch < 8; ch++) {
            vw += P.p[16][ch] * (wsp[96 +       b*8 + ch] * Li);
            vc += P.p[30][ch] * (wsp[96 + 256 + b*8 + ch] * Li);
        }
        float width  = vw;
        float center = fminf(fmaxf(vc, 1.0f), 128.0f);
        float cst[7];
        cst[0] = 0.56418958354775628f;            // 1/sqrt(pi)
#pragma unroll
        for (int i = 1; i < 7; i++) cst[i] = cst[i-1] * sqrtf(2.0f / (float)i);
        int k = tid;
        float t = width * ((float)k - center);
        float e = expf(-0.5f * t * t);
        float hpv = 1.0f, hc = 2.0f * t;
        kern[0][k] = e * cst[0];
        kern[1][k] = e * cst[1] * hc;
#pragma unroll
        for (int i = 2; i < 7; i++) {
            float hn = 2.0f*t*hc - 2.0f*(float)(i-1)*hpv;
            hpv = hc; hc = hn;
            kern[i][k] = e * cst[i] * hc;
        }
        kern[7][k] = 1.0f / (1.0f + expf(-2.0f * t));
    }
    __syncthreads();
    if (tid < 7) {
        float ss = 0.f;
#pragma unroll
        for (int k = 0; k < 9; k++) ss += kern[tid][k]*kern[tid][k];
        float inv = 1.0f / fmaxf(sqrtf(ss), 1e-12f);
#pragma unroll
        for (int k = 0; k < 9; k++) kern[tid][k] *= inv;
    }

    // ---- whole-sample output conv, 8 chunks of 1024 positions ----
    const float c2b = P.p[3][0];
    float* outp = out + (size_t)b*LEN;
    for (int ck = 0; ck < 8; ck++) {
        __syncthreads();                 // kern ready / previous chunk done
        {   // stage chunk [ck*1024-4, ck*1024+1028) into smem[ch][0..1031]
            int ch = tid >> 5, q = tid & 31;
            const float* src = x1 + ((size_t)b*ORD + ch)*LEN + ck*1024;
            float4* dst = reinterpret_cast<float4*>(&smem[ch][4]);
#pragma unroll
            for (int r = 0; r < 8; r++) {
                int f4 = q + 32*r;
                dst[f4] = reinterpret_cast<const float4*>(src)[f4];
            }
            if (tid < 64) {
                int hc = tid >> 3, hh = tid & 7;
                int l, idx;
                if (hh < 4) { l = ck*1024 - 4 + hh;        idx = hh; }
                else        { l = ck*1024 + 1024 + (hh-4); idx = 1028 + (hh-4); }
                smem[hc][idx] = ((unsigned)l < (unsigned)LEN)
                              ? x1[((size_t)b*ORD + hc)*LEN + l] : 0.f;
            }
        }
        __syncthreads();
#pragma unroll
        for (int q2 = 0; q2 < 4; q2++) {
            int p = tid + 256*q2;        // lanes stride-1 -> conflict-free
            float a = c2b;
#pragma unroll
            for (int c = 0; c < 8; c++)
#pragma unroll
                for (int j = 0; j < 9; j++) a += smem[c][p + j] * kern[c][j];
            outp[ck*1024 + p] = a;
        }
    }
}

// ---------------------------------------------------------------------------
extern "C" void kernel_launch(void* const* d_in, const int* in_sizes, int n_in,
                              void* d_out, int out_size, void* d_ws, size_t ws_size,
                              hipStream_t stream)
{
    (void)in_sizes; (void)n_in; (void)out_size; (void)ws_size;
    const float* x  = (const float*)d_in[0];
    const float* w1 = (const float*)d_in[1];
    const float* b1 = (const float*)d_in[2];
    float* outF = (float*)d_out;
    float* x1   = outF + (size_t)BATCH * LEN;   // second tuple output
    float* ws   = (float*)d_ws;

    Params P;
    for (int i = 0; i < 32; i++) P.p[i] = (const float*)d_in[i];

    hipMemsetAsync(d_ws, 0, 4096, stream);
    k1_gemm_stats<<<512, 256, 0, stream>>>(x, w1, b1, x1, ws, P);
    k3_stats     <<<512, 256, 0, stream>>>(x1, ws, P);
    k46_pool_out <<<512, 256, 0, stream>>>(x1, ws, P, outF);
}